// Round 3
// baseline (454.648 us; speedup 1.0000x reference)
//
#include <hip/hip_runtime.h>
#include <math.h>

// GraphTrainNN: out[b] = prod_g  w2*(wn + w0*x^2)/(wn + x^2), wn = w1^2.
// Memory-bound: ~266 MB read (~half L3-resident from harness restore) -> floor < 42 us.
//
// R2 lesson: LDS row-staging caps occupancy at 4 waves/CU (11% meas) -> 158 us,
// all pipes <11% busy. This version has NO LDS and NO barrier:
//   - thread owns 4 consecutive rows = 508 floats = 2032 B, which is 16B-aligned
//     (single rows, 508 B, are not) -> 127 float4 loads per thread, full lines
//     consumed by one thread, L1 absorbs the 4x line-touch (reuse dist ~12KB < 32KB).
//   - gene counter g and row-emit points are identical across lanes (every thread
//     starts at a 4-row boundary) -> wave-uniform control, zero divergence, and
//     weight reads wp[g] are uniform -> scalar-cache loads.
//   - mantissa/exponent renorm (frexpf every 8 elems, ldexpf at emit) avoids the
//     fp32 underflow->0/0=NaN hazard from R1; matches reference to <1e-38.

constexpr int G_GENES = 127;
constexpr int RPT = 4;    // rows per thread (4*127 floats = 2032 B, 16B aligned)
constexpr int BLK = 64;

__global__ __launch_bounds__(128)
void prep_weights(const float* __restrict__ w, float4* __restrict__ wp)
{
    int g = threadIdx.x;
    if (g < G_GENES) {
        float w0 = w[3 * g + 0];
        float w1 = w[3 * g + 1];
        float w2 = w[3 * g + 2];
        float wn = w1 * w1;
        wp[g] = make_float4(w0 * w2, wn * w2, wn, 0.0f);
    }
}

template <bool HAVE_PREP>
__global__ __launch_bounds__(BLK)
void hill4_kernel(const float* __restrict__ x,
                  const float4* __restrict__ wp,   // prepped (a,b,wn) per gene
                  const float* __restrict__ wraw,  // fallback raw (G,3)
                  float* __restrict__ out)
{
    const int tid = threadIdx.x;
    const size_t row0 = ((size_t)blockIdx.x * BLK + tid) * RPT;
    const float4* __restrict__ xp =
        reinterpret_cast<const float4*>(x + row0 * G_GENES);  // byte base = t*2032, 16B aligned
    float* __restrict__ op = out + row0;

    float pn = 1.0f, pd = 1.0f;
    int ex = 0;
    int g = 0, r = 0;

#pragma unroll 8
    for (int k = 0; k < G_GENES; ++k) {  // 127 float4 loads = 508 elements = 4 rows
        float4 xv = xp[k];
#pragma unroll
        for (int j = 0; j < 4; ++j) {
            float xe = (j == 0) ? xv.x : (j == 1) ? xv.y : (j == 2) ? xv.z : xv.w;
            float a, b, wn;
            if constexpr (HAVE_PREP) {
                float4 wv = wp[g];       // uniform index -> s_load
                a = wv.x; b = wv.y; wn = wv.z;
            } else {
                float w0 = wraw[3 * g + 0];
                float w1 = wraw[3 * g + 1];
                float w2 = wraw[3 * g + 2];
                wn = w1 * w1; a = w0 * w2; b = wn * w2;
            }
            float xn = xe * xe;
            pn *= fmaf(a, xn, b);        // w2*(wn + w0*xn)
            pd *= (wn + xn);
            ++g;
            if (g == G_GENES) {          // wave-uniform: row complete
                op[r] = ldexpf(pn / pd, ex);
                ++r; g = 0; pn = 1.0f; pd = 1.0f; ex = 0;
            }
            if (j == 3 && (k & 1)) {     // every 8 elements: renormalize mantissas
                int en, ed;
                pn = frexpf(pn, &en);
                pd = frexpf(pd, &ed);
                ex += en - ed;
            }
        }
    }
}

extern "C" void kernel_launch(void* const* d_in, const int* in_sizes, int n_in,
                              void* d_out, int out_size, void* d_ws, size_t ws_size,
                              hipStream_t stream) {
    const float* x = (const float*)d_in[0];
    const float* w = (const float*)d_in[1];
    float* out = (float*)d_out;

    const int B = in_sizes[0] / G_GENES;        // 524288
    const int blocks = B / (BLK * RPT);         // 2048

    if (ws_size >= G_GENES * sizeof(float4)) {
        float4* wp = (float4*)d_ws;
        hipLaunchKernelGGL(prep_weights, dim3(1), dim3(128), 0, stream, w, wp);
        hipLaunchKernelGGL((hill4_kernel<true>), dim3(blocks), dim3(BLK), 0, stream,
                           x, wp, w, out);
    } else {
        hipLaunchKernelGGL((hill4_kernel<false>), dim3(blocks), dim3(BLK), 0, stream,
                           x, nullptr, w, out);
    }
}

// Round 4
// 364.153 us; speedup vs baseline: 1.2485x; 1.2485x over previous
//
#include <hip/hip_runtime.h>
#include <math.h>

// out[b] = prod_g w2*(wn + w0*x^2)/(wn + x^2), wn = w1^2, G=127 genes/row.
//
// R2: full 64x127 LDS tile -> 4 waves/CU, 158 us (latency-bound, all pipes idle).
// R3: no-LDS strided float4/lane -> compiler rolled the loop (VGPR=12, no MLP)
//     and the 2032-B-strided lane pattern over-fetched 400 MB (vs 130 MB for
//     R2's coalesced staging). 203 us.
// R4: coalesced + high occupancy. Wave owns 64 rows, staged in 4 slabs of
//     16 rows (8128 B contiguous) via async global_load_lds width=16 into a
//     per-wave 8.1 KB buffer (no block barrier in the loop). 4 waves/block,
//     ~34 KB LDS/block -> 4 blocks/CU = 16 waves/CU; inter-wave overlap hides
//     each wave's vmcnt(0) stall. Compute: 4 lanes/row, genes interleaved
//     (gene=4t+q) -> float2 weight reads broadcast conflict-free, x reads <=4-way.
//     h factored as (w0*w2)*(xn + wn/w0)/(xn + wn): 2 consts/gene in the loop,
//     x-independent scale prod(w0*w2) computed once per lane. frexp renorm every
//     16 genes avoids fp32 underflow (R1's 0/0=NaN); ldexpf underflows cleanly.

constexpr int G = 127;
constexpr int WAVES = 4;
constexpr int BLK = WAVES * 64;
constexpr int ROWS_PER_WAVE = 64;
constexpr int SLAB_ROWS = 16;
constexpr int SLABS = ROWS_PER_WAVE / SLAB_ROWS;  // 4
constexpr int SLAB_FLOATS = SLAB_ROWS * G;        // 2032
constexpr int SLAB_F4 = SLAB_FLOATS / 4;          // 508 float4 per slab

struct __align__(16) Lds {
    float4 xbuf[WAVES][SLAB_F4];  // 4 x 8128 B, per-wave private
    float2 cw[G];                 // (wn/w0, wn)
    float  sw[G];                 // w0*w2
};

typedef const __attribute__((address_space(1))) void* gvp_t;
typedef __attribute__((address_space(3))) void* lvp_t;

__device__ __forceinline__ void stage_slab(const float* gbase, float4* lbase, int lane)
{
#pragma unroll
    for (int r = 0; r < (SLAB_F4 + 63) / 64; ++r) {  // 8 rounds (last: 60 lanes)
        int slot = r * 64 + lane;
        if (slot < SLAB_F4) {
            // lds dest is wave-uniform base + lane*16; gptr is per-lane.
            __builtin_amdgcn_global_load_lds((gvp_t)(gbase + (size_t)slot * 4),
                                             (lvp_t)(lbase + r * 64), 16, 0, 0);
        }
    }
}

__global__ __launch_bounds__(BLK, 4)
void hill_kernel(const float* __restrict__ x, const float* __restrict__ w,
                 float* __restrict__ out)
{
    __shared__ Lds lds;
    const int tid  = threadIdx.x;
    const int wave = tid >> 6;
    const int lane = tid & 63;
    const int q    = lane & 3;   // gene-phase: this lane handles genes 4t+q
    const int row  = lane >> 2;  // slab row 0..15

    // Per-block weight prep (once; only barrier in the kernel).
    if (tid < G) {
        float w0 = w[3 * tid + 0], w1 = w[3 * tid + 1], w2 = w[3 * tid + 2];
        float wn = w1 * w1;
        lds.cw[tid] = make_float2(wn / w0, wn);
        lds.sw[tid] = w0 * w2;
    }
    __syncthreads();

    // x-independent row scale: prod over this lane's genes of (w0*w2), renormed.
    float ps = 1.0f; int pse = 0;
#pragma unroll
    for (int h = 0; h < 2; ++h) {
#pragma unroll
        for (int t2 = 0; t2 < 16; ++t2) {
            int gene = 4 * (h * 16 + t2) + q;
            if (gene < G) ps *= lds.sw[gene];
        }
        int e; ps = frexpf(ps, &e); pse += e;
    }
#pragma unroll
    for (int d = 1; d <= 2; d <<= 1) {   // quad-combine: all 4 lanes get full scale
        float o = __shfl_xor(ps, d); int oe = __shfl_xor(pse, d);
        ps *= o; pse += oe;
    }
    { int e; ps = frexpf(ps, &e); pse += e; }

    const size_t tile_row0 = ((size_t)blockIdx.x * WAVES + wave) * ROWS_PER_WAVE;
    const float* xw = (const float*)&lds.xbuf[wave][0];
    float4* lb = &lds.xbuf[wave][0];

    for (int s = 0; s < SLABS; ++s) {
        if (s) __builtin_amdgcn_s_waitcnt(0xC07F);  // lgkmcnt(0): WAR on xbuf
        stage_slab(x + (tile_row0 + (size_t)s * SLAB_ROWS) * G, lb, lane);
        __builtin_amdgcn_s_waitcnt(0x3F70);         // vmcnt(0): slab landed

        float pn = 1.0f, pd = 1.0f; int ex = 0;
        const int rb = row * G;
#pragma unroll
        for (int h = 0; h < 2; ++h) {
#pragma unroll
            for (int t2 = 0; t2 < 16; ++t2) {
                int gene = 4 * (h * 16 + t2) + q;
                if (gene < G) {
                    float2 c = lds.cw[gene];      // conflict-free broadcast
                    float xv = xw[rb + gene];     // <=4-way bank conflict
                    float xn = xv * xv;
                    pn *= (xn + c.x);             // xn + wn/w0
                    pd *= (xn + c.y);             // xn + wn
                }
            }
            int e1, e2;
            pn = frexpf(pn, &e1); pd = frexpf(pd, &e2); ex += e1 - e2;
        }
        // combine the 4 gene-phases of this row
#pragma unroll
        for (int d = 1; d <= 2; d <<= 1) {
            float o1 = __shfl_xor(pn, d), o2 = __shfl_xor(pd, d);
            int   o3 = __shfl_xor(ex, d);
            pn *= o1; pd *= o2; ex += o3;
        }
        if (q == 0)
            out[tile_row0 + s * SLAB_ROWS + row] = ldexpf(ps * pn / pd, ex + pse);
    }
}

extern "C" void kernel_launch(void* const* d_in, const int* in_sizes, int n_in,
                              void* d_out, int out_size, void* d_ws, size_t ws_size,
                              hipStream_t stream) {
    const float* x = (const float*)d_in[0];
    const float* w = (const float*)d_in[1];
    float* out = (float*)d_out;

    const int B = in_sizes[0] / G;          // 524288
    const int blocks = B / BLK;             // 2048 (exact)

    hipLaunchKernelGGL(hill_kernel, dim3(blocks), dim3(BLK), 0, stream, x, w, out);
}

// Round 5
// 363.858 us; speedup vs baseline: 1.2495x; 1.0008x over previous
//
#include <hip/hip_runtime.h>
#include <math.h>

// out[b] = prod_g w2*(wn + w0*x^2)/(wn + x^2), wn = w1^2, G=127 genes/row.
//
// R2: 64x127 LDS tile, 4 waves/CU               -> 158 us (latency-bound).
// R3: no-LDS strided float4/lane                -> 203 us (rolled loop, 400 MB fetch).
// R4: per-wave 16-row slabs, global_load_lds,
//     16 waves/CU, but serial stage->vmcnt(0)->compute per wave -> ~112 us.
// R5: software-pipelined double buffer in the SAME 8128 B/wave LDS footprint:
//     8 slabs of 8 rows, issue s and s+1 ahead, wait vmcnt(4) (prev slab landed,
//     next in flight), compute, issue s+2. Wave keeps ~8 KB in flight always.
//     Compute slimmed: per-lane gene set is loop-invariant -> weights hoisted to
//     registers (cr[16]); gene order rotated by row so x LDS reads are <=2-way
//     (free); invalid gene 127 handled branchlessly with neutral (1,1) weights
//     (factor (xn+1)/(xn+1) = 1). frexp renorm every 8 genes avoids fp32
//     underflow (R1: 0/0=NaN); ldexpf underflows cleanly to 0 like the reference.

constexpr int G = 127;
constexpr int WAVES = 4;
constexpr int BLK = WAVES * 64;
constexpr int ROWS_PER_WAVE = 64;
constexpr int SLAB_ROWS = 8;
constexpr int SLABS = ROWS_PER_WAVE / SLAB_ROWS;  // 8
constexpr int SLAB_FLOATS = SLAB_ROWS * G;        // 1016
constexpr int SLAB_F4 = SLAB_FLOATS / 4;          // 254 float4 per slab
constexpr int GPL = 16;                           // genes per lane (8 lanes/row)

struct __align__(16) Lds {
    float4 xbuf[WAVES][2 * SLAB_F4];  // per-wave double buffer, 2 x 4064 B
    float2 cw[G];                     // (wn/w0, wn)
    float  sw[G];                     // w0*w2
};

typedef const __attribute__((address_space(1))) void* gvp_t;
typedef __attribute__((address_space(3))) void* lvp_t;

// Stage one 8-row slab (1016 floats, contiguous, coalesced 16B/lane).
// LDS dest must be wave-uniform base (+lane*16 applied by HW).
__device__ __forceinline__ void stage(const float* g0, float4* l0, int lane)
{
#pragma unroll
    for (int r = 0; r < 4; ++r) {            // 4 rounds (last: 62 lanes)
        int slot = r * 64 + lane;
        if (slot < SLAB_F4)
            __builtin_amdgcn_global_load_lds((gvp_t)(g0 + (size_t)slot * 4),
                                             (lvp_t)(l0 + r * 64), 16, 0, 0);
    }
}

__global__ __launch_bounds__(BLK, 4)
void hill_kernel(const float* __restrict__ x, const float* __restrict__ w,
                 float* __restrict__ out)
{
    __shared__ Lds lds;
    const int tid  = threadIdx.x;
    const int wave = tid >> 6;
    const int lane = tid & 63;
    const int q    = lane & 7;   // gene phase within row
    const int row  = lane >> 3;  // slab row 0..7

    if (tid < G) {
        float w0 = w[3 * tid], w1 = w[3 * tid + 1], w2 = w[3 * tid + 2];
        float wn = w1 * w1;
        lds.cw[tid] = make_float2(wn / w0, wn);
        lds.sw[tid] = w0 * w2;
    }
    __syncthreads();

    // Loop-invariant per-lane setup: weights into regs, x offsets into regs,
    // x-independent scale prod(w0*w2) over all 127 genes (combined over the
    // 8 lanes of the row group; identical for every row group).
    float2 cr[GPL];
    int    off[GPL];
    float  ps = 1.0f; int pse = 0;
#pragma unroll
    for (int t = 0; t < GPL; ++t) {
        int gene = 8 * ((t + row) & 15) + q;  // row-rotated: x reads <=2-way banks
        bool v = gene < G;
        int ga = v ? gene : 0;
        float2 c = lds.cw[ga];
        cr[t] = v ? c : make_float2(1.0f, 1.0f);  // neutral factor
        if (v) ps *= lds.sw[ga];
        off[t] = row * G + ga;
        if ((t & 7) == 7) { int e; ps = frexpf(ps, &e); pse += e; }
    }
#pragma unroll
    for (int d = 1; d <= 4; d <<= 1) {
        ps  *= __shfl_xor(ps, d);
        pse += __shfl_xor(pse, d);
    }
    { int e; ps = frexpf(ps, &e); pse += e; }

    const size_t tile_row0 = ((size_t)blockIdx.x * WAVES + wave) * ROWS_PER_WAVE;
    const float* xg = x + tile_row0 * G;
    float4* b0 = &lds.xbuf[wave][0];
    const float* xf = (const float*)b0;

    // Prime the pipeline: slabs 0 and 1 in flight.
    stage(xg, b0, lane);
    stage(xg + SLAB_FLOATS, b0 + SLAB_F4, lane);

#pragma unroll
    for (int s = 0; s < SLABS; ++s) {
        // Wait for slab s only; slab s+1 stays in flight.
        if (s < SLABS - 1) __builtin_amdgcn_s_waitcnt(0x3F74);  // vmcnt(4)
        else               __builtin_amdgcn_s_waitcnt(0x3F70);  // vmcnt(0)

        const float* xb = xf + (s & 1) * SLAB_FLOATS;
        float pn = 1.0f, pd = 1.0f; int ex = 0;
#pragma unroll
        for (int t = 0; t < GPL; ++t) {
            float xv = xb[off[t]];        // ds_read_b32, <=2-way bank alias
            float xn = xv * xv;
            pn *= (xn + cr[t].x);         // xn + wn/w0
            pd *= (xn + cr[t].y);         // xn + wn
            if ((t & 7) == 7) {
                int e1, e2;
                pn = frexpf(pn, &e1); pd = frexpf(pd, &e2); ex += e1 - e2;
            }
        }

        // Refill the half we just consumed (DMA lands >>100 cyc later; the
        // ds_reads above are already drained into the product chain).
        if (s + 2 < SLABS)
            stage(xg + (size_t)(s + 2) * SLAB_FLOATS, b0 + (s & 1) * SLAB_F4, lane);

        // Combine the 8 gene-phases of each row.
#pragma unroll
        for (int d = 1; d <= 4; d <<= 1) {
            pn *= __shfl_xor(pn, d);
            pd *= __shfl_xor(pd, d);
            ex += __shfl_xor(ex, d);
        }
        if (q == 0)
            out[tile_row0 + s * SLAB_ROWS + row] = ldexpf(ps * pn / pd, ex + pse);
    }
}

extern "C" void kernel_launch(void* const* d_in, const int* in_sizes, int n_in,
                              void* d_out, int out_size, void* d_ws, size_t ws_size,
                              hipStream_t stream) {
    const float* x = (const float*)d_in[0];
    const float* w = (const float*)d_in[1];
    float* out = (float*)d_out;

    const int B = in_sizes[0] / G;   // 524288
    const int blocks = B / BLK;      // 2048

    hipLaunchKernelGGL(hill_kernel, dim3(blocks), dim3(BLK), 0, stream, x, w, out);
}